// Round 6
// baseline (312.483 us; speedup 1.0000x reference)
//
#include <hip/hip_runtime.h>
#include <hip/hip_bf16.h>

// R6: R5's k_fused was overhead-bound (MfmaUtil 11%, 5.7M LDS write conflicts
// from 64 scalar b16 y-tile writes/thread, W restaged via LDS 2x per t).
// Double-transposed fusion: conv computes D[m=h][n=bn] (A=Krev, B=x) so the
// y-tile is written with 8 packed ds_write_b64/thread into [bn][h]; GLU GEMM
// computes D[m=j][n=bn] (A=W register-persistent from global — no W staging,
// B=y-tile b128 reads). 64-bn blocks (52KB LDS) -> 2 blocks/CU.

#define B_  16
#define T_  354
#define N_  64
#define H_  128
#define NS_ 32
#define BN_ (B_*N_)          // 1024 sequences
#define TP_ 384              // padded tau range for xbf rows
#define KW_ 512              // padded Krev row length
#define PAD_ 136             // LDS row stride (bf16 elems): 16B-aligned rows
#define G_  4                // t's per fused block
#define NG_ ((T_ + G_ - 1) / G_)   // 89 t-groups

typedef __attribute__((ext_vector_type(8))) short bf16x8;
typedef __attribute__((ext_vector_type(4))) float f32x4;

static __device__ __forceinline__ unsigned short f32_to_bf16(float f) {
    unsigned int u = __float_as_uint(f);
    unsigned int r = 0x7FFFu + ((u >> 16) & 1u);   // RNE
    return (unsigned short)((u + r) >> 16);
}

// async global->LDS, 4 B per lane: one 256 B row per instruction.
static __device__ __forceinline__ void gload_lds4(const void* g, void* l) {
    __builtin_amdgcn_global_load_lds(
        (const __attribute__((address_space(1))) unsigned int*)g,
        (__attribute__((address_space(3))) unsigned int*)l, 4, 0, 0);
}

// gelu(v) = v * sigmoid(1.595769122*v + 0.071354816*v^3)  (tanh approx, JAX)
static __device__ __forceinline__ float gelu_f(float v) {
    float v2 = v * v;
    float x  = v * fmaf(0.0713548162726f, v2, 1.5957691216057f);
    float sg = 1.0f / (1.0f + __expf(-x));
    return v * sg;
}

// ---------------------------------------------------------------------------
// K0: merged prep.  blocks [0,128): S4D kernel taps for h=blockIdx.
//   K'[h,l] = 2*Sum_m Re(Cd[h,m]*exp(dtA*l)) (+D[h] at l=0)
//   Krev_r[h][(353-l)+r] = bf16(K'), r=0..7;  koff[t][h]=b_in[h]*cumsum K'
// blocks [128,900): xbf bf16 transpose-cast + W_out bf16 cast.
// ---------------------------------------------------------------------------
__global__ __launch_bounds__(512) void k_pre(
        const float* __restrict__ log_dt,
        const float* __restrict__ A_re, const float* __restrict__ A_im,
        const float* __restrict__ C_re, const float* __restrict__ C_im,
        const float* __restrict__ b_in, const float* __restrict__ D,
        const float* __restrict__ x, const float* __restrict__ W_out,
        unsigned short* __restrict__ Krev, float* __restrict__ koff,
        unsigned short* __restrict__ xbf, unsigned short* __restrict__ Wbf) {
    if (blockIdx.x >= H_) {
        int id = (blockIdx.x - H_) * 512 + threadIdx.x;
        if (id < T_ * BN_) {
            int t  = id >> 10;
            int bn = id & 1023;
            float v = x[(bn >> 6) * (T_ * N_) + t * N_ + (bn & 63)];
            xbf[bn * TP_ + t] = f32_to_bf16(v);
        } else {
            int i = id - T_ * BN_;
            if (i < 2 * H_ * H_) Wbf[i] = f32_to_bf16(W_out[i]);
        }
        return;
    }

    const int h = blockIdx.x;
    const int l = threadIdx.x;

    float val = 0.0f;
    if (l < T_) {
        float dt = expf(log_dt[h]);
        float fl = (float)l;
#pragma unroll 4
        for (int m = 0; m < NS_; m++) {
            float are = A_re[h * NS_ + m], aim = A_im[h * NS_ + m];
            float dre = are * dt, dim = aim * dt;
            float er  = expf(dre);
            float c1, s1; __sincosf(dim, &s1, &c1);
            float e_re = er * c1, e_im = er * s1;
            float m_re = e_re - 1.0f, m_im = e_im;
            float inv  = 1.0f / (are * are + aim * aim);
            float q_re = (m_re * are + m_im * aim) * inv;
            float q_im = (m_im * are - m_re * aim) * inv;
            float c_r = C_re[h * NS_ + m], c_i = C_im[h * NS_ + m];
            float cdre = c_r * q_re - c_i * q_im;
            float cdim = c_r * q_im + c_i * q_re;
            float el = expf(dre * fl);
            float cl, sl; __sincosf(dim * fl, &sl, &cl);
            val += el * (cdre * cl - cdim * sl);
        }
        val *= 2.0f;
        if (l == 0) val += D[h];
    }

    __shared__ float sc[512];
    sc[l] = (l < T_) ? val : 0.0f;
    __syncthreads();
    for (int off = 1; off < 512; off <<= 1) {
        float add = (l >= off) ? sc[l - off] : 0.0f;
        __syncthreads();
        sc[l] += add;
        __syncthreads();
    }

    if (l < T_) {
        koff[l * H_ + h] = b_in[h] * sc[l];
        unsigned short bv = f32_to_bf16(val);
#pragma unroll
        for (int r = 0; r < 8; r++)
            Krev[((size_t)r * H_ + h) * KW_ + (T_ - 1 - l) + r] = bv;
    }
}

// ---------------------------------------------------------------------------
// K1: fused conv + gelu + W_out GEMM + GLU + t-pool  (double-transposed).
// Block = 256 thr / 4 waves, tile = 64 bn x 128 h x G_ t's.
// Conv:  D[m=h][n=bn], A = Krev windows (k_lds), B = xbf rows (x_lds).
// y-tile: gelu'd conv out packed to ds_write_b64 into x_lds alias [bn][h].
// GEMM:  D[m=j][n=bn], A = W frags (16 VGPR-resident, loaded once),
//        B = y-tile b128 reads.  GLU+pool in regs; one atomic per elem/block.
// ---------------------------------------------------------------------------
__global__ __launch_bounds__(256, 2) void k_fused(
        const unsigned short* __restrict__ xbf,    // [1024][TP_]
        const unsigned short* __restrict__ Krev,   // [8][128][KW_]
        const float* __restrict__ koff,            // [354][128]
        const float* __restrict__ W_in,
        const unsigned short* __restrict__ Wbf,    // [256][128]
        const float* __restrict__ b_out,
        float* __restrict__ node_sum) {
    __shared__ unsigned short x_lds[64 * PAD_];    // x tile / y tile (17 KB)
    __shared__ unsigned short k_lds[128 * PAD_];   // Krev tile (34 KB)

    const int tid  = threadIdx.x;
    const int w    = tid >> 6;
    const int lane = tid & 63;
    const int q    = lane >> 4;
    const int l16  = lane & 15;
    const int bn0  = blockIdx.x * 64;
    const int tg0  = blockIdx.y * G_;

    // ---- W a-frags, register-persistent: wave w owns j in [32w,32w+32) + 128 ----
    bf16x8 wfrag[4][4];                            // [mtJ][ks]
#pragma unroll
    for (int mt = 0; mt < 4; mt++) {
        int jb = 32 * w + 16 * (mt & 1) + 128 * (mt >> 1);
#pragma unroll
        for (int ks = 0; ks < 4; ks++)
            wfrag[mt][ks] = *(const bf16x8*)(Wbf + (size_t)(jb + l16) * H_ + ks * 32 + q * 8);
    }

    float win[2][4], bo1[2][4], bo2[2][4];
#pragma unroll
    for (int mt = 0; mt < 2; mt++)
#pragma unroll
        for (int rr = 0; rr < 4; rr++) {
            int hj = 32 * w + 16 * mt + 4 * q + rr;
            win[mt][rr] = W_in[hj];
            bo1[mt][rr] = b_out[hj];
            bo2[mt][rr] = b_out[128 + hj];
        }

    f32x4 zacc[2][4];
#pragma unroll
    for (int mt = 0; mt < 2; mt++)
#pragma unroll
        for (int nt = 0; nt < 4; nt++) zacc[mt][nt] = (f32x4){0.f, 0.f, 0.f, 0.f};

    for (int g = 0; g < G_; g++) {
        const int t = tg0 + g;
        if (t >= T_) break;                        // block-uniform
        const int nkb = (t >> 7) + 1;

        float ko[2][4];
#pragma unroll
        for (int mt = 0; mt < 2; mt++)
#pragma unroll
            for (int rr = 0; rr < 4; rr++)
                ko[mt][rr] = koff[t * H_ + 32 * w + 16 * mt + 4 * q + rr];

        // ---- conv: cacc[h-tiles][bn-tiles], D[m=h][n=bn] ----
        f32x4 cacc[2][4];
#pragma unroll
        for (int mt = 0; mt < 2; mt++)
#pragma unroll
            for (int nt = 0; nt < 4; nt++) cacc[mt][nt] = (f32x4){0.f, 0.f, 0.f, 0.f};

        for (int kb = 0; kb < nkb; kb++) {
            const int tau0 = kb << 7;
            const int L    = 353 - t + tau0;       // >= 0
            const int cp   = (-L) & 7;             // copy-select -> 16B align
            __syncthreads();                       // prior readers done
            // stage x: 64 rows, wave w stages rows [16w,16w+16)
#pragma unroll
            for (int i = 0; i < 16; i++) {
                int r = w * 16 + i;
                gload_lds4(xbf + (size_t)(bn0 + r) * TP_ + tau0 + lane * 2,
                           &x_lds[r * PAD_]);
            }
            // stage Krev windows: 128 rows, wave w stages rows [32w,32w+32)
#pragma unroll 8
            for (int i = 0; i < 32; i++) {
                int hr = w * 32 + i;
                gload_lds4(Krev + ((size_t)cp * H_ + hr) * KW_ + (L + cp) + lane * 2,
                           &k_lds[hr * PAD_]);
            }
            __syncthreads();

#pragma unroll
            for (int ks = 0; ks < 4; ks++) {
                bf16x8 af[2], bf[4];
#pragma unroll
                for (int mt = 0; mt < 2; mt++)     // A: lane=h-row
                    af[mt] = *(const bf16x8*)&k_lds[(32 * w + 16 * mt + l16) * PAD_ + ks * 32 + q * 8];
#pragma unroll
                for (int nt = 0; nt < 4; nt++)     // B: lane=bn-col
                    bf[nt] = *(const bf16x8*)&x_lds[(16 * nt + l16) * PAD_ + ks * 32 + q * 8];
#pragma unroll
                for (int mt = 0; mt < 2; mt++)
#pragma unroll
                    for (int nt = 0; nt < 4; nt++)
                        cacc[mt][nt] = __builtin_amdgcn_mfma_f32_16x16x32_bf16(
                            af[mt], bf[nt], cacc[mt][nt], 0, 0, 0);
            }
        }

        // ---- epilogue: y = gelu(win*cacc + ko) -> packed b64 into [bn][h] ----
        __syncthreads();                           // conv reads of x_lds done
#pragma unroll
        for (int mt = 0; mt < 2; mt++)
#pragma unroll
            for (int nt = 0; nt < 4; nt++) {
                unsigned short pk[4];
#pragma unroll
                for (int rr = 0; rr < 4; rr++) {
                    float v = fmaf(cacc[mt][nt][rr], win[mt][rr], ko[mt][rr]);
                    pk[rr] = f32_to_bf16(gelu_f(v));
                }
                // bn = 16nt+l16, h0 = 32w+16mt+4q  (rr consecutive in h)
                *(uint2*)&x_lds[(16 * nt + l16) * PAD_ + 32 * w + 16 * mt + 4 * q]
                    = *(const uint2*)pk;
            }
        __syncthreads();

        // ---- GLU GEMM: D[m=j][n=bn], A=wfrag (regs), B=y-tile ----
        f32x4 gacc[4][4];
#pragma unroll
        for (int mt = 0; mt < 4; mt++)
#pragma unroll
            for (int nt = 0; nt < 4; nt++) gacc[mt][nt] = (f32x4){0.f, 0.f, 0.f, 0.f};
#pragma unroll
        for (int ks = 0; ks < 4; ks++) {
            bf16x8 yf[4];
#pragma unroll
            for (int nt = 0; nt < 4; nt++)
                yf[nt] = *(const bf16x8*)&x_lds[(16 * nt + l16) * PAD_ + ks * 32 + q * 8];
#pragma unroll
            for (int mt = 0; mt < 4; mt++)
#pragma unroll
                for (int nt = 0; nt < 4; nt++)
                    gacc[mt][nt] = __builtin_amdgcn_mfma_f32_16x16x32_bf16(
                        wfrag[mt][ks], yf[nt], gacc[mt][nt], 0, 0, 0);
        }

        // ---- GLU + t-pool (registers) ----
#pragma unroll
        for (int mt = 0; mt < 2; mt++)
#pragma unroll
            for (int nt = 0; nt < 4; nt++)
#pragma unroll
                for (int rr = 0; rr < 4; rr++) {
                    float a  = gacc[mt][nt][rr] + bo1[mt][rr];
                    float bs = gacc[mt + 2][nt][rr] + bo2[mt][rr];
                    float sg = 1.0f / (1.0f + __expf(-bs));
                    zacc[mt][nt][rr] += a * sg;
                }
    }

    // ---- flush pooled z ----
#pragma unroll
    for (int mt = 0; mt < 2; mt++)
#pragma unroll
        for (int nt = 0; nt < 4; nt++)
#pragma unroll
            for (int rr = 0; rr < 4; rr++) {
                int bn = bn0 + 16 * nt + l16;
                int j  = 32 * w + 16 * mt + 4 * q + rr;
                atomicAdd(&node_sum[bn * H_ + j], zacc[mt][nt][rr]);
            }
}

// ---------------------------------------------------------------------------
// K2: logits[b] = (1/(T*N)) * sum_{n,h} node_sum[b*64+n][h] * W_cls[h] + b_cls
// ---------------------------------------------------------------------------
__global__ void k_cls(const float* __restrict__ node_sum,
                      const float* __restrict__ W_cls, const float* __restrict__ b_cls,
                      float* __restrict__ out) {
    const int b = blockIdx.x, tid = threadIdx.x;
    float s = 0.0f;
    for (int i = tid; i < N_ * H_; i += 256)
        s += node_sum[b * (N_ * H_) + i] * W_cls[i & (H_ - 1)];
    __shared__ float red[256];
    red[tid] = s;
    __syncthreads();
    for (int off = 128; off > 0; off >>= 1) {
        if (tid < off) red[tid] += red[tid + off];
        __syncthreads();
    }
    if (tid == 0) out[b] = red[0] * (1.0f / (354.0f * 64.0f)) + b_cls[0];
}

// ---------------------------------------------------------------------------
extern "C" void kernel_launch(void* const* d_in, const int* in_sizes, int n_in,
                              void* d_out, int out_size, void* d_ws, size_t ws_size,
                              hipStream_t stream) {
    const float* x      = (const float*)d_in[0];
    const float* W_in   = (const float*)d_in[1];
    const float* b_in   = (const float*)d_in[2];
    const float* log_dt = (const float*)d_in[3];
    const float* A_re   = (const float*)d_in[4];
    const float* A_im   = (const float*)d_in[5];
    const float* C_re   = (const float*)d_in[6];
    const float* C_im   = (const float*)d_in[7];
    const float* D      = (const float*)d_in[8];
    const float* W_out  = (const float*)d_in[9];
    const float* b_out  = (const float*)d_in[10];
    const float* W_cls  = (const float*)d_in[11];
    const float* b_cls  = (const float*)d_in[12];

    char* ws = (char*)d_ws;
    // [node_sum 512K][xbf 768K][Krev 1M] contiguous -> ONE memset
    float*          node_sum = (float*)(ws + 0);                  //   524288 B
    unsigned short* xbf      = (unsigned short*)(ws + 524288);    //   786432 B
    unsigned short* Krev     = (unsigned short*)(ws + 1310720);   //  1048576 B
    float*          koff     = (float*)(ws + 2359296);            //   181248 B
    unsigned short* Wbf      = (unsigned short*)(ws + 2540544);   //    65536 B

    hipMemsetAsync(ws, 0, 2359296, stream);
    const int prep_blocks = (T_ * BN_ + 2 * H_ * H_ + 511) / 512;
    k_pre<<<dim3(H_ + prep_blocks), dim3(512), 0, stream>>>(
        log_dt, A_re, A_im, C_re, C_im, b_in, D, x, W_out, Krev, koff, xbf, Wbf);
    k_fused<<<dim3(BN_ / 64, NG_), dim3(256), 0, stream>>>(
        xbf, Krev, koff, W_in, Wbf, b_out, node_sum);
    k_cls<<<dim3(B_), dim3(256), 0, stream>>>(node_sum, W_cls, b_cls, (float*)d_out);
}

// Round 7
// 285.435 us; speedup vs baseline: 1.0948x; 1.0948x over previous
//
#include <hip/hip_runtime.h>
#include <hip/hip_bf16.h>

// R7: R6 regressed via scratch spills (WRITE_SIZE 66->206MB at identical
// atomic count; 128 VGPR + 128 AGPR budget at launch_bounds(256,2) overflowed
// by persistent wfrag + cacc/gacc/zacc). Fix: wfrag reloaded from L2 per t
// (loads issued before the gelu epilogue to hide latency), G_=8 halves block
// count & atomic writebacks, conv ks-loop bounded by t (taps>t are zero).
// Layouts identical to R6 (verified): conv D[m=h][n=bn], y-tile packed b64
// into [bn][h], GLU D[m=j][n=bn] with B=y-tile b128 reads.

#define B_  16
#define T_  354
#define N_  64
#define H_  128
#define NS_ 32
#define BN_ (B_*N_)          // 1024 sequences
#define TP_ 384              // padded tau range for xbf rows
#define KW_ 512              // padded Krev row length
#define PAD_ 136             // LDS row stride (bf16 elems)
#define G_  8                // t's per fused block
#define NG_ ((T_ + G_ - 1) / G_)   // 45 t-groups

typedef __attribute__((ext_vector_type(8))) short bf16x8;
typedef __attribute__((ext_vector_type(4))) float f32x4;

static __device__ __forceinline__ unsigned short f32_to_bf16(float f) {
    unsigned int u = __float_as_uint(f);
    unsigned int r = 0x7FFFu + ((u >> 16) & 1u);   // RNE
    return (unsigned short)((u + r) >> 16);
}

// async global->LDS, 4 B per lane: one 256 B row per instruction.
static __device__ __forceinline__ void gload_lds4(const void* g, void* l) {
    __builtin_amdgcn_global_load_lds(
        (const __attribute__((address_space(1))) unsigned int*)g,
        (__attribute__((address_space(3))) unsigned int*)l, 4, 0, 0);
}

// gelu(v) = v * sigmoid(1.595769122*v + 0.071354816*v^3)  (tanh approx, JAX)
static __device__ __forceinline__ float gelu_f(float v) {
    float v2 = v * v;
    float x  = v * fmaf(0.0713548162726f, v2, 1.5957691216057f);
    float sg = 1.0f / (1.0f + __expf(-x));
    return v * sg;
}

// ---------------------------------------------------------------------------
// K0: merged prep.  blocks [0,128): S4D kernel taps for h=blockIdx.
//   K'[h,l] = 2*Sum_m Re(Cd[h,m]*exp(dtA*l)) (+D[h] at l=0)
//   Krev_r[h][(353-l)+r] = bf16(K'), r=0..7;  koff[t][h]=b_in[h]*cumsum K'
// blocks [128,...): xbf bf16 transpose-cast + W_out bf16 cast.
// ---------------------------------------------------------------------------
__global__ __launch_bounds__(512) void k_pre(
        const float* __restrict__ log_dt,
        const float* __restrict__ A_re, const float* __restrict__ A_im,
        const float* __restrict__ C_re, const float* __restrict__ C_im,
        const float* __restrict__ b_in, const float* __restrict__ D,
        const float* __restrict__ x, const float* __restrict__ W_out,
        unsigned short* __restrict__ Krev, float* __restrict__ koff,
        unsigned short* __restrict__ xbf, unsigned short* __restrict__ Wbf) {
    if (blockIdx.x >= H_) {
        int id = (blockIdx.x - H_) * 512 + threadIdx.x;
        if (id < T_ * BN_) {
            int t  = id >> 10;
            int bn = id & 1023;
            float v = x[(bn >> 6) * (T_ * N_) + t * N_ + (bn & 63)];
            xbf[bn * TP_ + t] = f32_to_bf16(v);
        } else {
            int i = id - T_ * BN_;
            if (i < 2 * H_ * H_) Wbf[i] = f32_to_bf16(W_out[i]);
        }
        return;
    }

    const int h = blockIdx.x;
    const int l = threadIdx.x;

    float val = 0.0f;
    if (l < T_) {
        float dt = expf(log_dt[h]);
        float fl = (float)l;
#pragma unroll 4
        for (int m = 0; m < NS_; m++) {
            float are = A_re[h * NS_ + m], aim = A_im[h * NS_ + m];
            float dre = are * dt, dim = aim * dt;
            float er  = expf(dre);
            float c1, s1; __sincosf(dim, &s1, &c1);
            float e_re = er * c1, e_im = er * s1;
            float m_re = e_re - 1.0f, m_im = e_im;
            float inv  = 1.0f / (are * are + aim * aim);
            float q_re = (m_re * are + m_im * aim) * inv;
            float q_im = (m_im * are - m_re * aim) * inv;
            float c_r = C_re[h * NS_ + m], c_i = C_im[h * NS_ + m];
            float cdre = c_r * q_re - c_i * q_im;
            float cdim = c_r * q_im + c_i * q_re;
            float el = expf(dre * fl);
            float cl, sl; __sincosf(dim * fl, &sl, &cl);
            val += el * (cdre * cl - cdim * sl);
        }
        val *= 2.0f;
        if (l == 0) val += D[h];
    }

    __shared__ float sc[512];
    sc[l] = (l < T_) ? val : 0.0f;
    __syncthreads();
    for (int off = 1; off < 512; off <<= 1) {
        float add = (l >= off) ? sc[l - off] : 0.0f;
        __syncthreads();
        sc[l] += add;
        __syncthreads();
    }

    if (l < T_) {
        koff[l * H_ + h] = b_in[h] * sc[l];
        unsigned short bv = f32_to_bf16(val);
#pragma unroll
        for (int r = 0; r < 8; r++)
            Krev[((size_t)r * H_ + h) * KW_ + (T_ - 1 - l) + r] = bv;
    }
}

// ---------------------------------------------------------------------------
// K1: fused conv + gelu + W_out GEMM + GLU + t-pool.
// Block = 256 thr / 4 waves, tile = 64 bn x 128 h x G_ t's.
// Conv:  D[m=h][n=bn], A = Krev windows (k_lds), B = xbf rows (x_lds),
//        ks-loop bounded by (t - tau0)>>5 (higher taps are zero).
// y-tile: gelu'd conv out packed b64 into x_lds alias [bn][h].
// GEMM:  D[m=j][n=bn], A = W frags reloaded from L2 per t (issued before the
//        gelu epilogue to hide latency), B = y-tile b128 reads.
// GLU+pool in regs; one atomic per elem per block.
// ---------------------------------------------------------------------------
__global__ __launch_bounds__(256, 2) void k_fused(
        const unsigned short* __restrict__ xbf,    // [1024][TP_]
        const unsigned short* __restrict__ Krev,   // [8][128][KW_]
        const float* __restrict__ koff,            // [354][128]
        const float* __restrict__ W_in,
        const unsigned short* __restrict__ Wbf,    // [256][128]
        const float* __restrict__ b_out,
        float* __restrict__ node_sum) {
    __shared__ unsigned short x_lds[64 * PAD_];    // x tile / y tile (17 KB)
    __shared__ unsigned short k_lds[128 * PAD_];   // Krev tile (34 KB)

    const int tid  = threadIdx.x;
    const int w    = tid >> 6;
    const int lane = tid & 63;
    const int q    = lane >> 4;
    const int l16  = lane & 15;
    const int bn0  = blockIdx.x * 64;
    const int tg0  = blockIdx.y * G_;

    float win[2][4], bo1[2][4], bo2[2][4];
#pragma unroll
    for (int mt = 0; mt < 2; mt++)
#pragma unroll
        for (int rr = 0; rr < 4; rr++) {
            int hj = 32 * w + 16 * mt + 4 * q + rr;
            win[mt][rr] = W_in[hj];
            bo1[mt][rr] = b_out[hj];
            bo2[mt][rr] = b_out[128 + hj];
        }

    f32x4 zacc[2][4];
#pragma unroll
    for (int mt = 0; mt < 2; mt++)
#pragma unroll
        for (int nt = 0; nt < 4; nt++) zacc[mt][nt] = (f32x4){0.f, 0.f, 0.f, 0.f};

    for (int g = 0; g < G_; g++) {
        const int t = tg0 + g;
        if (t >= T_) break;                        // block-uniform
        const int nkb = (t >> 7) + 1;

        float ko[2][4];
#pragma unroll
        for (int mt = 0; mt < 2; mt++)
#pragma unroll
            for (int rr = 0; rr < 4; rr++)
                ko[mt][rr] = koff[t * H_ + 32 * w + 16 * mt + 4 * q + rr];

        // ---- conv: D[m=h][n=bn] ----
        f32x4 cacc[2][4];
#pragma unroll
        for (int mt = 0; mt < 2; mt++)
#pragma unroll
            for (int nt = 0; nt < 4; nt++) cacc[mt][nt] = (f32x4){0.f, 0.f, 0.f, 0.f};

        for (int kb = 0; kb < nkb; kb++) {
            const int tau0 = kb << 7;
            const int L    = 353 - t + tau0;       // >= 0
            const int cp   = (-L) & 7;             // copy-select -> 16B align
            const int kshi = min(3, (t - tau0) >> 5);
            __syncthreads();                       // prior readers done
#pragma unroll
            for (int i = 0; i < 16; i++) {
                int r = w * 16 + i;
                gload_lds4(xbf + (size_t)(bn0 + r) * TP_ + tau0 + lane * 2,
                           &x_lds[r * PAD_]);
            }
#pragma unroll 8
            for (int i = 0; i < 32; i++) {
                int hr = w * 32 + i;
                gload_lds4(Krev + ((size_t)cp * H_ + hr) * KW_ + (L + cp) + lane * 2,
                           &k_lds[hr * PAD_]);
            }
            __syncthreads();

            for (int ks = 0; ks <= kshi; ks++) {
                bf16x8 af[2], bf[4];
#pragma unroll
                for (int mt = 0; mt < 2; mt++)     // A: lane=h-row
                    af[mt] = *(const bf16x8*)&k_lds[(32 * w + 16 * mt + l16) * PAD_ + ks * 32 + q * 8];
#pragma unroll
                for (int nt = 0; nt < 4; nt++)     // B: lane=bn-col
                    bf[nt] = *(const bf16x8*)&x_lds[(16 * nt + l16) * PAD_ + ks * 32 + q * 8];
#pragma unroll
                for (int mt = 0; mt < 2; mt++)
#pragma unroll
                    for (int nt = 0; nt < 4; nt++)
                        cacc[mt][nt] = __builtin_amdgcn_mfma_f32_16x16x32_bf16(
                            af[mt], bf[nt], cacc[mt][nt], 0, 0, 0);
            }
        }

        // ---- W a-frags for this t (L2-hot; issued before epilogue VALU) ----
        bf16x8 wfrag[4][4];                        // [mtJ][ks]
#pragma unroll
        for (int mt = 0; mt < 4; mt++) {
            int jb = 32 * w + 16 * (mt & 1) + 128 * (mt >> 1);
#pragma unroll
            for (int ks = 0; ks < 4; ks++)
                wfrag[mt][ks] = *(const bf16x8*)(Wbf + (size_t)(jb + l16) * H_ + ks * 32 + q * 8);
        }

        // ---- epilogue: y = gelu(win*cacc + ko) -> packed b64 into [bn][h] ----
        __syncthreads();                           // conv reads of x_lds done
#pragma unroll
        for (int mt = 0; mt < 2; mt++)
#pragma unroll
            for (int nt = 0; nt < 4; nt++) {
                unsigned short pk[4];
#pragma unroll
                for (int rr = 0; rr < 4; rr++) {
                    float v = fmaf(cacc[mt][nt][rr], win[mt][rr], ko[mt][rr]);
                    pk[rr] = f32_to_bf16(gelu_f(v));
                }
                // bn = 16nt+l16, h0 = 32w+16mt+4q  (rr consecutive in h)
                *(uint2*)&x_lds[(16 * nt + l16) * PAD_ + 32 * w + 16 * mt + 4 * q]
                    = *(const uint2*)pk;
            }
        __syncthreads();

        // ---- GLU GEMM: D[m=j][n=bn], A=wfrag, B=y-tile ----
        f32x4 gacc[4][4];
#pragma unroll
        for (int mt = 0; mt < 4; mt++)
#pragma unroll
            for (int nt = 0; nt < 4; nt++) gacc[mt][nt] = (f32x4){0.f, 0.f, 0.f, 0.f};
#pragma unroll
        for (int ks = 0; ks < 4; ks++) {
            bf16x8 yf[4];
#pragma unroll
            for (int nt = 0; nt < 4; nt++)
                yf[nt] = *(const bf16x8*)&x_lds[(16 * nt + l16) * PAD_ + ks * 32 + q * 8];
#pragma unroll
            for (int mt = 0; mt < 4; mt++)
#pragma unroll
                for (int nt = 0; nt < 4; nt++)
                    gacc[mt][nt] = __builtin_amdgcn_mfma_f32_16x16x32_bf16(
                        wfrag[mt][ks], yf[nt], gacc[mt][nt], 0, 0, 0);
        }

        // ---- GLU + t-pool (registers) ----
#pragma unroll
        for (int mt = 0; mt < 2; mt++)
#pragma unroll
            for (int nt = 0; nt < 4; nt++)
#pragma unroll
                for (int rr = 0; rr < 4; rr++) {
                    float a  = gacc[mt][nt][rr] + bo1[mt][rr];
                    float bs = gacc[mt + 2][nt][rr] + bo2[mt][rr];
                    float sg = 1.0f / (1.0f + __expf(-bs));
                    zacc[mt][nt][rr] += a * sg;
                }
    }

    // ---- flush pooled z ----
#pragma unroll
    for (int mt = 0; mt < 2; mt++)
#pragma unroll
        for (int nt = 0; nt < 4; nt++)
#pragma unroll
            for (int rr = 0; rr < 4; rr++) {
                int bn = bn0 + 16 * nt + l16;
                int j  = 32 * w + 16 * mt + 4 * q + rr;
                atomicAdd(&node_sum[bn * H_ + j], zacc[mt][nt][rr]);
            }
}

// ---------------------------------------------------------------------------
// K2: logits[b] = (1/(T*N)) * sum_{n,h} node_sum[b*64+n][h] * W_cls[h] + b_cls
// ---------------------------------------------------------------------------
__global__ void k_cls(const float* __restrict__ node_sum,
                      const float* __restrict__ W_cls, const float* __restrict__ b_cls,
                      float* __restrict__ out) {
    const int b = blockIdx.x, tid = threadIdx.x;
    float s = 0.0f;
    for (int i = tid; i < N_ * H_; i += 256)
        s += node_sum[b * (N_ * H_) + i] * W_cls[i & (H_ - 1)];
    __shared__ float red[256];
    red[tid] = s;
    __syncthreads();
    for (int off = 128; off > 0; off >>= 1) {
        if (tid < off) red[tid] += red[tid + off];
        __syncthreads();
    }
    if (tid == 0) out[b] = red[0] * (1.0f / (354.0f * 64.0f)) + b_cls[0];
}

// ---------------------------------------------------------------------------
extern "C" void kernel_launch(void* const* d_in, const int* in_sizes, int n_in,
                              void* d_out, int out_size, void* d_ws, size_t ws_size,
                              hipStream_t stream) {
    const float* x      = (const float*)d_in[0];
    const float* W_in   = (const float*)d_in[1];
    const float* b_in   = (const float*)d_in[2];
    const float* log_dt = (const float*)d_in[3];
    const float* A_re   = (const float*)d_in[4];
    const float* A_im   = (const float*)d_in[5];
    const float* C_re   = (const float*)d_in[6];
    const float* C_im   = (const float*)d_in[7];
    const float* D      = (const float*)d_in[8];
    const float* W_out  = (const float*)d_in[9];
    const float* b_out  = (const float*)d_in[10];
    const float* W_cls  = (const float*)d_in[11];
    const float* b_cls  = (const float*)d_in[12];

    char* ws = (char*)d_ws;
    // [node_sum 512K][xbf 768K][Krev 1M] contiguous -> ONE memset
    float*          node_sum = (float*)(ws + 0);                  //   524288 B
    unsigned short* xbf      = (unsigned short*)(ws + 524288);    //   786432 B
    unsigned short* Krev     = (unsigned short*)(ws + 1310720);   //  1048576 B
    float*          koff     = (float*)(ws + 2359296);            //   181248 B
    unsigned short* Wbf      = (unsigned short*)(ws + 2540544);   //    65536 B

    hipMemsetAsync(ws, 0, 2359296, stream);
    const int prep_blocks = (T_ * BN_ + 2 * H_ * H_ + 511) / 512;
    k_pre<<<dim3(H_ + prep_blocks), dim3(512), 0, stream>>>(
        log_dt, A_re, A_im, C_re, C_im, b_in, D, x, W_out, Krev, koff, xbf, Wbf);
    k_fused<<<dim3(BN_ / 64, NG_), dim3(256), 0, stream>>>(
        xbf, Krev, koff, W_in, Wbf, b_out, node_sum);
    k_cls<<<dim3(B_), dim3(256), 0, stream>>>(node_sum, W_cls, b_cls, (float*)d_out);
}

// Round 10
// 243.904 us; speedup vs baseline: 1.2812x; 1.1703x over previous
//
#include <hip/hip_runtime.h>
#include <hip/hip_bf16.h>

// R10: R9 still failed because the restructured k_pre gave the Wbf cast only
// 8 blocks (4096 writes for 32768 elems -> 7/8 of W_out was 0xAA poison;
// absmax 7e-2 = bias-only GLU rows). Fix: 64 cast blocks. Transpose (fixed
// in R9) verified. Rest identical to R8 split design: k_conv (conv+gelu ->
// coalesced Y[q][h], 3 blocks/CU) + k_glu (16 j-pairs/wave, 4 blocks/CU,
// j-contiguous atomic flush).

#define B_  16
#define T_  354
#define N_  64
#define H_  128
#define NS_ 32
#define BN_ (B_*N_)          // 1024 sequences
#define TP_ 384              // padded tau range for xbf rows
#define KW_ 512              // padded Krev row length
#define PAD_ 136             // LDS row stride (bf16 elems)
#define GC_ 4                // t's per k_conv block
#define NGC_ ((T_ + GC_ - 1) / GC_)   // 89
#define GT_ 16               // t's per k_glu block
#define NGT_ ((T_ + GT_ - 1) / GT_)   // 23
#define WB_ ((2 * H_ * H_) / 512)     // 64 Wbf-cast blocks

typedef __attribute__((ext_vector_type(8))) short bf16x8;
typedef __attribute__((ext_vector_type(4))) float f32x4;

static __device__ __forceinline__ unsigned short f32_to_bf16(float f) {
    unsigned int u = __float_as_uint(f);
    unsigned int r = 0x7FFFu + ((u >> 16) & 1u);   // RNE
    return (unsigned short)((u + r) >> 16);
}

// async global->LDS, 4 B per lane: one 256 B row per instruction.
static __device__ __forceinline__ void gload_lds4(const void* g, void* l) {
    __builtin_amdgcn_global_load_lds(
        (const __attribute__((address_space(1))) unsigned int*)g,
        (__attribute__((address_space(3))) unsigned int*)l, 4, 0, 0);
}

// gelu(v) = v * sigmoid(1.595769122*v + 0.071354816*v^3)  (tanh approx, JAX)
static __device__ __forceinline__ float gelu_f(float v) {
    float v2 = v * v;
    float x  = v * fmaf(0.0713548162726f, v2, 1.5957691216057f);
    float sg = 1.0f / (1.0f + __expf(-x));
    return v * sg;
}

// ---------------------------------------------------------------------------
// K0: merged prep, role by blockIdx.x:
//  [0,128):        S4D taps for h=blockIdx (+ Krev 8 copies + koff scan)
//  [128,224):      x transpose-cast via LDS (64t x 64n tile)
//  [224,224+WB_):  W_out f32 -> bf16 (one elem/thread, 64 blocks)
// ---------------------------------------------------------------------------
__global__ __launch_bounds__(512) void k_pre(
        const float* __restrict__ log_dt,
        const float* __restrict__ A_re, const float* __restrict__ A_im,
        const float* __restrict__ C_re, const float* __restrict__ C_im,
        const float* __restrict__ b_in, const float* __restrict__ D,
        const float* __restrict__ x, const float* __restrict__ W_out,
        unsigned short* __restrict__ Krev, float* __restrict__ koff,
        unsigned short* __restrict__ xbf, unsigned short* __restrict__ Wbf) {
    const int blk = blockIdx.x;
    const int tid = threadIdx.x;

    if (blk >= H_ + 96) {                          // ---- Wbf cast ----
        int id = (blk - H_ - 96) * 512 + tid;
        if (id < 2 * H_ * H_) Wbf[id] = f32_to_bf16(W_out[id]);
        return;
    }
    if (blk >= H_) {                               // ---- x transpose ----
        __shared__ float xt[64][68];               // +4 pad
        int idx = blk - H_;
        int bt = idx / 6, tt = idx % 6;            // b-index, t-tile
        int r  = tid >> 3, fc = tid & 7;           // row, col-octet
        int t  = tt * 64 + r;
        float4 v0 = make_float4(0.f, 0.f, 0.f, 0.f), v1 = v0;
        if (t < T_) {
            const float* xp = x + ((size_t)bt * T_ + t) * N_ + fc * 8;
            v0 = *(const float4*)xp;
            v1 = *(const float4*)(xp + 4);
        }
        *(float4*)&xt[r][fc * 8]     = v0;         // 2 float4 = all 64 cols
        *(float4*)&xt[r][fc * 8 + 4] = v1;
        __syncthreads();
        int n = tid >> 3, tc = tid & 7;
        unsigned short pk[8];
#pragma unroll
        for (int k = 0; k < 8; k++) pk[k] = f32_to_bf16(xt[tc * 8 + k][n]);
        *(uint4*)(xbf + (size_t)(bt * 64 + n) * TP_ + tt * 64 + tc * 8)
            = *(const uint4*)pk;
        return;
    }

    // ---- taps ----
    const int h = blk;
    const int l = tid;
    float val = 0.0f;
    if (l < T_) {
        float dt = expf(log_dt[h]);
        float fl = (float)l;
#pragma unroll 4
        for (int m = 0; m < NS_; m++) {
            float are = A_re[h * NS_ + m], aim = A_im[h * NS_ + m];
            float dre = are * dt, dim = aim * dt;
            float er  = expf(dre);
            float c1, s1; __sincosf(dim, &s1, &c1);
            float e_re = er * c1, e_im = er * s1;
            float m_re = e_re - 1.0f, m_im = e_im;
            float inv  = 1.0f / (are * are + aim * aim);
            float q_re = (m_re * are + m_im * aim) * inv;
            float q_im = (m_im * are - m_re * aim) * inv;
            float c_r = C_re[h * NS_ + m], c_i = C_im[h * NS_ + m];
            float cdre = c_r * q_re - c_i * q_im;
            float cdim = c_r * q_im + c_i * q_re;
            float el = expf(dre * fl);
            float cl, sl; __sincosf(dim * fl, &sl, &cl);
            val += el * (cdre * cl - cdim * sl);
        }
        val *= 2.0f;
        if (l == 0) val += D[h];
    }

    __shared__ float sc[512];
    sc[l] = (l < T_) ? val : 0.0f;
    __syncthreads();
    for (int off = 1; off < 512; off <<= 1) {
        float add = (l >= off) ? sc[l - off] : 0.0f;
        __syncthreads();
        sc[l] += add;
        __syncthreads();
    }

    if (l < T_) {
        koff[l * H_ + h] = b_in[h] * sc[l];
        unsigned short bv = f32_to_bf16(val);
#pragma unroll
        for (int r = 0; r < 8; r++)
            Krev[((size_t)r * H_ + h) * KW_ + (T_ - 1 - l) + r] = bv;
    }
}

// ---------------------------------------------------------------------------
// K1: conv + gelu -> Y[q][h] (coalesced b128 stores via LDS y-tile).
// Block = 256 thr / 4 waves, tile = 64 bn x 128 h x GC_ t's.
// Conv D[m=h][n=bn]: A = Krev windows (k_lds), B = xbf rows (x_lds),
// ks-loop bounded by t (taps>t are zero).
// ---------------------------------------------------------------------------
__global__ __launch_bounds__(256, 3) void k_conv(
        const unsigned short* __restrict__ xbf,    // [1024][TP_]
        const unsigned short* __restrict__ Krev,   // [8][128][KW_]
        const float* __restrict__ koff,            // [354][128]
        const float* __restrict__ W_in,
        unsigned short* __restrict__ Y) {          // [q][h]
    __shared__ unsigned short x_lds[64 * PAD_];    // x tile / y tile (17 KB)
    __shared__ unsigned short k_lds[128 * PAD_];   // Krev tile (34 KB)

    const int tid  = threadIdx.x;
    const int w    = tid >> 6;
    const int lane = tid & 63;
    const int q    = lane >> 4;
    const int l16  = lane & 15;
    const int bn0  = blockIdx.x * 64;
    const int tg0  = blockIdx.y * GC_;

    float win[2][4];
#pragma unroll
    for (int mt = 0; mt < 2; mt++)
#pragma unroll
        for (int rr = 0; rr < 4; rr++)
            win[mt][rr] = W_in[32 * w + 16 * mt + 4 * q + rr];

    for (int g = 0; g < GC_; g++) {
        const int t = tg0 + g;
        if (t >= T_) break;                        // block-uniform
        const int nkb = (t >> 7) + 1;

        float ko[2][4];
#pragma unroll
        for (int mt = 0; mt < 2; mt++)
#pragma unroll
            for (int rr = 0; rr < 4; rr++)
                ko[mt][rr] = koff[t * H_ + 32 * w + 16 * mt + 4 * q + rr];

        f32x4 cacc[2][4];
#pragma unroll
        for (int mt = 0; mt < 2; mt++)
#pragma unroll
            for (int nt = 0; nt < 4; nt++) cacc[mt][nt] = (f32x4){0.f, 0.f, 0.f, 0.f};

        for (int kb = 0; kb < nkb; kb++) {
            const int tau0 = kb << 7;
            const int L    = 353 - t + tau0;       // >= 0
            const int cp   = (-L) & 7;             // copy-select -> 16B align
            const int kshi = min(3, (t - tau0) >> 5);
            __syncthreads();                       // prior readers done
#pragma unroll
            for (int i = 0; i < 16; i++) {
                int r = w * 16 + i;
                gload_lds4(xbf + (size_t)(bn0 + r) * TP_ + tau0 + lane * 2,
                           &x_lds[r * PAD_]);
            }
#pragma unroll 8
            for (int i = 0; i < 32; i++) {
                int hr = w * 32 + i;
                gload_lds4(Krev + ((size_t)cp * H_ + hr) * KW_ + (L + cp) + lane * 2,
                           &k_lds[hr * PAD_]);
            }
            __syncthreads();

            for (int ks = 0; ks <= kshi; ks++) {
                bf16x8 af[2], bf[4];
#pragma unroll
                for (int mt = 0; mt < 2; mt++)     // A: lane=h-row
                    af[mt] = *(const bf16x8*)&k_lds[(32 * w + 16 * mt + l16) * PAD_ + ks * 32 + q * 8];
#pragma unroll
                for (int nt = 0; nt < 4; nt++)     // B: lane=bn-col
                    bf[nt] = *(const bf16x8*)&x_lds[(16 * nt + l16) * PAD_ + ks * 32 + q * 8];
#pragma unroll
                for (int mt = 0; mt < 2; mt++)
#pragma unroll
                    for (int nt = 0; nt < 4; nt++)
                        cacc[mt][nt] = __builtin_amdgcn_mfma_f32_16x16x32_bf16(
                            af[mt], bf[nt], cacc[mt][nt], 0, 0, 0);
            }
        }

        // ---- epilogue: y = gelu(win*cacc + ko) -> packed b64 into [bn][h] ----
        __syncthreads();                           // conv reads of x_lds done
#pragma unroll
        for (int mt = 0; mt < 2; mt++)
#pragma unroll
            for (int nt = 0; nt < 4; nt++) {
                unsigned short pk[4];
#pragma unroll
                for (int rr = 0; rr < 4; rr++) {
                    float v = fmaf(cacc[mt][nt][rr], win[mt][rr], ko[mt][rr]);
                    pk[rr] = f32_to_bf16(gelu_f(v));
                }
                *(uint2*)&x_lds[(16 * nt + l16) * PAD_ + 32 * w + 16 * mt + 4 * q]
                    = *(const uint2*)pk;
            }
        __syncthreads();

        // ---- coalesced store: 64 rows x 256B to Y[q][h] ----
#pragma unroll
        for (int i = 0; i < 4; i++) {
            int c    = i * 256 + tid;
            int row  = c >> 4;
            int col8 = (c & 15) * 8;
            uint4 v = *(const uint4*)&x_lds[row * PAD_ + col8];
            *(uint4*)(Y + ((size_t)t * BN_ + bn0 + row) * H_ + col8) = v;
        }
    }
}

// ---------------------------------------------------------------------------
// K2: GLU GEMM + t-pool.  D[m=j][n=bn], A = W frags (VGPR-persistent, 16
// j-pairs per wave), B = Y-tile staged per t.  Flush: 16 consecutive j per
// line (coalesced atomic write-through).
// ---------------------------------------------------------------------------
__global__ __launch_bounds__(256, 4) void k_glu(
        const unsigned short* __restrict__ Y,      // [q][h]
        const unsigned short* __restrict__ Wbf,    // [256][128]
        const float* __restrict__ b_out,
        float* __restrict__ node_sum) {
    __shared__ unsigned short Yt[64 * PAD_];       // 17 KB

    const int tid  = threadIdx.x;
    const int w    = tid >> 6;
    const int lane = tid & 63;
    const int q    = lane >> 4;
    const int l16  = lane & 15;
    const int jg   = blockIdx.x & 1;
    const int bn0  = (blockIdx.x >> 1) * 64;
    const int tg0  = blockIdx.y * GT_;
    const int jlow = jg * 64 + w * 16;             // wave's low-j row base
    const int jhigh = jlow + 128;

    bf16x8 wfrag[2][4];                            // [low/high][ks]
#pragma unroll
    for (int ks = 0; ks < 4; ks++) {
        wfrag[0][ks] = *(const bf16x8*)(Wbf + (size_t)(jlow  + l16) * H_ + ks * 32 + q * 8);
        wfrag[1][ks] = *(const bf16x8*)(Wbf + (size_t)(jhigh + l16) * H_ + ks * 32 + q * 8);
    }
    float bo1[4], bo2[4];
#pragma unroll
    for (int rr = 0; rr < 4; rr++) {
        bo1[rr] = b_out[jlow  + 4 * q + rr];
        bo2[rr] = b_out[jhigh + 4 * q + rr];
    }

    f32x4 zacc[4];
#pragma unroll
    for (int nt = 0; nt < 4; nt++) zacc[nt] = (f32x4){0.f, 0.f, 0.f, 0.f};

    for (int g = 0; g < GT_; g++) {
        const int t = tg0 + g;
        if (t >= T_) break;                        // block-uniform
        __syncthreads();
#pragma unroll
        for (int i = 0; i < 16; i++) {
            int r = w * 16 + i;
            gload_lds4(Y + ((size_t)t * BN_ + bn0 + r) * H_ + lane * 2,
                       &Yt[r * PAD_]);
        }
        __syncthreads();

        f32x4 gacc[2][4];
#pragma unroll
        for (int mt = 0; mt < 2; mt++)
#pragma unroll
            for (int nt = 0; nt < 4; nt++) gacc[mt][nt] = (f32x4){0.f, 0.f, 0.f, 0.f};

#pragma unroll
        for (int ks = 0; ks < 4; ks++) {
            bf16x8 yf[4];
#pragma unroll
            for (int nt = 0; nt < 4; nt++)
                yf[nt] = *(const bf16x8*)&Yt[(16 * nt + l16) * PAD_ + ks * 32 + q * 8];
#pragma unroll
            for (int mt = 0; mt < 2; mt++)
#pragma unroll
                for (int nt = 0; nt < 4; nt++)
                    gacc[mt][nt] = __builtin_amdgcn_mfma_f32_16x16x32_bf16(
                        wfrag[mt][ks], yf[nt], gacc[mt][nt], 0, 0, 0);
        }

#pragma unroll
        for (int nt = 0; nt < 4; nt++)
#pragma unroll
            for (int rr = 0; rr < 4; rr++) {
                float a  = gacc[0][nt][rr] + bo1[rr];
                float bs = gacc[1][nt][rr] + bo2[rr];
                float sg = 1.0f / (1.0f + __expf(-bs));
                zacc[nt][rr] += a * sg;
            }
    }

    // flush: lanes sharing a 64B line (16 consecutive j at fixed bn)
#pragma unroll
    for (int nt = 0; nt < 4; nt++)
#pragma unroll
        for (int rr = 0; rr < 4; rr++) {
            int bn = bn0 + 16 * nt + l16;
            int j  = jlow + 4 * q + rr;
            atomicAdd(&node_sum[bn * H_ + j], zacc[nt][rr]);
        }
}

// ---------------------------------------------------------------------------
// K3: logits[b] = (1/(T*N)) * sum_{n,h} node_sum[b*64+n][h] * W_cls[h] + b_cls
// ---------------------------------------------------------------------------
__global__ void k_cls(const float* __restrict__ node_sum,
                      const float* __restrict__ W_cls, const float* __restrict__ b_cls,
                      float* __restrict__ out) {
    const int b = blockIdx.x, tid = threadIdx.x;
    float s = 0.0f;
    for (int i = tid; i < N_ * H_; i += 256)
        s += node_sum[b * (N_ * H_) + i] * W_cls[i & (H_ - 1)];
    __shared__ float red[256];
    red[tid] = s;
    __syncthreads();
    for (int off = 128; off > 0; off >>= 1) {
        if (tid < off) red[tid] += red[tid + off];
        __syncthreads();
    }
    if (tid == 0) out[b] = red[0] * (1.0f / (354.0f * 64.0f)) + b_cls[0];
}

// ---------------------------------------------------------------------------
extern "C" void kernel_launch(void* const* d_in, const int* in_sizes, int n_in,
                              void* d_out, int out_size, void* d_ws, size_t ws_size,
                              hipStream_t stream) {
    const float* x      = (const float*)d_in[0];
    const float* W_in   = (const float*)d_in[1];
    const float* b_in   = (const float*)d_in[2];
    const float* log_dt = (const float*)d_in[3];
    const float* A_re   = (const float*)d_in[4];
    const float* A_im   = (const float*)d_in[5];
    const float* C_re   = (const float*)d_in[6];
    const float* C_im   = (const float*)d_in[7];
    const float* D      = (const float*)d_in[8];
    const float* W_out  = (const float*)d_in[9];
    const float* b_out  = (const float*)d_in[10];
    const float* W_cls  = (const float*)d_in[11];
    const float* b_cls  = (const float*)d_in[12];

    char* ws = (char*)d_ws;
    // [node_sum 512K][Krev 1M] contiguous -> ONE memset; rest fully written
    float*          node_sum = (float*)(ws + 0);                  //   524288 B
    unsigned short* Krev     = (unsigned short*)(ws + 524288);    //  1048576 B
    float*          koff     = (float*)(ws + 1572864);            //   181248 B
    unsigned short* xbf      = (unsigned short*)(ws + 1754112);   //   786432 B
    unsigned short* Wbf      = (unsigned short*)(ws + 2540544);   //    65536 B
    unsigned short* Y        = (unsigned short*)(ws + 2606080);   // 92798976 B

    hipMemsetAsync(ws, 0, 1572864, stream);
    k_pre<<<dim3(H_ + 96 + WB_), dim3(512), 0, stream>>>(
        log_dt, A_re, A_im, C_re, C_im, b_in, D, x, W_out, Krev, koff, xbf, Wbf);
    k_conv<<<dim3(BN_ / 64, NGC_), dim3(256), 0, stream>>>(
        xbf, Krev, koff, W_in, Y);
    k_glu<<<dim3(2 * BN_ / 64, NGT_), dim3(256), 0, stream>>>(
        Y, Wbf, b_out, node_sum);
    k_cls<<<dim3(B_), dim3(256), 0, stream>>>(node_sum, W_cls, b_cls, (float*)d_out);
}